// Round 1
// baseline (97.326 us; speedup 1.0000x reference)
//
#include <hip/hip_runtime.h>
#include <math.h>

#define N_ROWS 16384
#define N_COLS 1000
#define WAVES_PER_BLOCK 4
#define MAIN_BLOCKS (N_ROWS / WAVES_PER_BLOCK)   // 4096

// ---------------------------------------------------------------------------
// Kernel 1: bincount of labels into ws (as float), single block.
// 16384 int reads = 64 KB; LDS atomics; negligible time.
// ---------------------------------------------------------------------------
__global__ __launch_bounds__(1024) void bincount_kernel(
    const int* __restrict__ label, float* __restrict__ counts) {
  __shared__ int cnt[N_COLS];
  for (int i = threadIdx.x; i < N_COLS; i += 1024) cnt[i] = 0;
  __syncthreads();
  for (int j = threadIdx.x; j < N_ROWS; j += 1024) {
    atomicAdd(&cnt[label[j]], 1);
  }
  __syncthreads();
  for (int i = threadIdx.x; i < N_COLS; i += 1024) counts[i] = (float)cnt[i];
}

// ---------------------------------------------------------------------------
// Kernel 2: one wave (64 lanes) per row. Row of 1000 f32 staged in 16 regs
// per lane via 4x coalesced float4 loads. Wave shfl reductions for max and
// sum(exp). Per-block partial sum written to ws (no atomics).
// ---------------------------------------------------------------------------
__global__ __launch_bounds__(256) void rowloss_kernel(
    const float* __restrict__ feature, const int* __restrict__ label,
    const float* __restrict__ counts, float* __restrict__ partial) {
  const int wave = threadIdx.x >> 6;
  const int lane = threadIdx.x & 63;
  const int row  = blockIdx.x * WAVES_PER_BLOCK + wave;

  const float* rowp = feature + (size_t)row * N_COLS;

  // Coalesced register staging: k-th step covers elements [k*256, k*256+256)
  // lane l takes the float4 at element k*256 + l*4. 1000 % 4 == 0 so any
  // in-bounds float4 is fully in-bounds. Row base is 4000 B -> 16B aligned.
  float4 v[4];
#pragma unroll
  for (int k = 0; k < 4; ++k) {
    const int e = k * 256 + lane * 4;
    if (e < N_COLS) {
      v[k] = *reinterpret_cast<const float4*>(rowp + e);
    } else {
      v[k] = make_float4(-INFINITY, -INFINITY, -INFINITY, -INFINITY);
    }
  }

  // Row max
  float m = -INFINITY;
#pragma unroll
  for (int k = 0; k < 4; ++k) {
    m = fmaxf(m, fmaxf(fmaxf(v[k].x, v[k].y), fmaxf(v[k].z, v[k].w)));
  }
#pragma unroll
  for (int off = 32; off > 0; off >>= 1) m = fmaxf(m, __shfl_xor(m, off));

  // sum(exp(x - m)) via exp2 (maps to v_exp_f32); -inf pads contribute 0.
  const float LOG2E = 1.4426950408889634f;
  const float mL = m * LOG2E;
  float s = 0.0f;
#pragma unroll
  for (int k = 0; k < 4; ++k) {
    s += exp2f(fmaf(v[k].x, LOG2E, -mL));
    s += exp2f(fmaf(v[k].y, LOG2E, -mL));
    s += exp2f(fmaf(v[k].z, LOG2E, -mL));
    s += exp2f(fmaf(v[k].w, LOG2E, -mL));
  }
#pragma unroll
  for (int off = 32; off > 0; off >>= 1) s += __shfl_xor(s, off);

  __shared__ float wsum[WAVES_PER_BLOCK];
  if (lane == 0) {
    const int lab = label[row];
    const float xl = rowp[lab];          // L1/L2 hit (row just streamed)
    const float logp = xl - m - logf(s); // log_softmax at label
    const float p = expf(logp);
    float b = 1.0f - p;
    b = b * b;                           // (1-p)^2
    const float ni = counts[lab];        // >= 1 always (row itself counted)
    const float r = ni * (1.0f / (float)N_ROWS);
    const float alpha = expf(r - 1.0f) / r;
    wsum[wave] = alpha * b * logp;       // picked value (negative)
  }
  __syncthreads();
  if (threadIdx.x == 0) {
    partial[blockIdx.x] = wsum[0] + wsum[1] + wsum[2] + wsum[3];
  }
}

// ---------------------------------------------------------------------------
// Kernel 3: reduce 4096 partials -> loss = -sum/N. Single block.
// ---------------------------------------------------------------------------
__global__ __launch_bounds__(1024) void reduce_kernel(
    const float* __restrict__ partial, float* __restrict__ out) {
  __shared__ float lds[1024];
  float s = 0.0f;
  for (int i = threadIdx.x; i < MAIN_BLOCKS; i += 1024) s += partial[i];
  lds[threadIdx.x] = s;
  __syncthreads();
  for (int off = 512; off > 0; off >>= 1) {
    if (threadIdx.x < off) lds[threadIdx.x] += lds[threadIdx.x + off];
    __syncthreads();
  }
  if (threadIdx.x == 0) out[0] = -lds[0] * (1.0f / (float)N_ROWS);
}

// ---------------------------------------------------------------------------
extern "C" void kernel_launch(void* const* d_in, const int* in_sizes, int n_in,
                              void* d_out, int out_size, void* d_ws, size_t ws_size,
                              hipStream_t stream) {
  const float* feature = (const float*)d_in[0];
  const int*   label   = (const int*)d_in[1];
  float* counts  = (float*)d_ws;            // [0, 1000) floats
  float* partial = (float*)d_ws + 1024;     // [1024, 1024+4096) floats
  float* out     = (float*)d_out;

  bincount_kernel<<<1, 1024, 0, stream>>>(label, counts);
  rowloss_kernel<<<MAIN_BLOCKS, 256, 0, stream>>>(feature, label, counts, partial);
  reduce_kernel<<<1, 1024, 0, stream>>>(partial, out);
}